// Round 8
// baseline (415.387 us; speedup 1.0000x reference)
//
#include <hip/hip_runtime.h>
#include <type_traits>

#define N_NODES 50000

using short8  = __attribute__((ext_vector_type(8))) short;
using floatx4 = __attribute__((ext_vector_type(4))) float;
using f32x2   = __attribute__((ext_vector_type(2))) float;

__device__ inline unsigned short f2b(float f) {
    unsigned u = __float_as_uint(f);
    u += 0x7FFFu + ((u >> 16) & 1u);           // RNE
    return (unsigned short)(u >> 16);
}
__device__ inline float b2f(unsigned short h) {
    return __uint_as_float(((unsigned)h) << 16);
}

// packed f32 FMA (VOP3P). Operands here are always freshly-loaded short-lived
// values (LDS weight reads / ea pairs), so the "v" constraints cost nothing —
// the round-0..6 pathology (per-use AGPR->VGPR copies) only applied to
// long-lived loop-invariant arrays, which now live in LDS instead.
// pk_fma_lo: d.{lo,hi} = a.lo * b.{lo,hi} + c.{lo,hi}
__device__ inline f32x2 pk_fma_lo(f32x2 a, f32x2 b, f32x2 c) {
    f32x2 d;
    asm("v_pk_fma_f32 %0, %1, %2, %3 op_sel_hi:[0,1,1]"
        : "=v"(d) : "v"(a), "v"(b), "v"(c));
    return d;
}
// pk_fma_hi: d.{lo,hi} = a.hi * b.{lo,hi} + c.{lo,hi}
__device__ inline f32x2 pk_fma_hi(f32x2 a, f32x2 b, f32x2 c) {
    f32x2 d;
    asm("v_pk_fma_f32 %0, %1, %2, %3 op_sel:[1,0,0] op_sel_hi:[1,1,1]"
        : "=v"(d) : "v"(a), "v"(b), "v"(c));
    return d;
}
__device__ inline f32x2 vrelu(f32x2 a) {
    return __builtin_elementwise_max(a, f32x2{0.f, 0.f});
}

// ---------------------------------------------------------------------------
// CSR build
// ---------------------------------------------------------------------------
__global__ __launch_bounds__(256) void zero_int_kernel(int* __restrict__ p, int n)
{
    int i = blockIdx.x * 256 + threadIdx.x;
    if (i < n) p[i] = 0;
}

__global__ __launch_bounds__(256) void hist_kernel(const int* __restrict__ dstv,
                                                   int* __restrict__ cnt, int E)
{
    int e = blockIdx.x * 256 + threadIdx.x;
    if (e < E) atomicAdd(&cnt[dstv[e]], 1);
}

__global__ __launch_bounds__(256) void scanA_kernel(const int* __restrict__ cnt,
                                                    int* __restrict__ row_start,
                                                    int* __restrict__ bsum, int n)
{
    __shared__ int s[256];
    int t = threadIdx.x;
    int i = blockIdx.x * 256 + t;
    int val = (i < n) ? cnt[i] : 0;
    s[t] = val;
    __syncthreads();
#pragma unroll
    for (int off = 1; off < 256; off <<= 1) {
        int v = (t >= off) ? s[t - off] : 0;
        __syncthreads();
        s[t] += v;
        __syncthreads();
    }
    if (i < n) row_start[i] = s[t] - val;
    if (t == 255) bsum[blockIdx.x] = s[255];
}

__global__ __launch_bounds__(256) void scanB_kernel(int* __restrict__ bsum, int nb)
{
    __shared__ int s[256];
    int t = threadIdx.x;
    int val = (t < nb) ? bsum[t] : 0;
    s[t] = val;
    __syncthreads();
#pragma unroll
    for (int off = 1; off < 256; off <<= 1) {
        int v = (t >= off) ? s[t - off] : 0;
        __syncthreads();
        s[t] += v;
        __syncthreads();
    }
    if (t < nb) bsum[t] = s[t] - val;
}

__global__ __launch_bounds__(256) void scanC_kernel(int* __restrict__ row_start,
                                                    int* __restrict__ woff,
                                                    const int* __restrict__ bsum, int n)
{
    int i = blockIdx.x * 256 + threadIdx.x;
    if (i < n) {
        int v = row_start[i] + bsum[blockIdx.x];
        row_start[i] = v;
        woff[i] = v;
    }
}

__global__ __launch_bounds__(256) void scatter_kernel(const int* __restrict__ srcv,
                                                      const int* __restrict__ dstv,
                                                      int* __restrict__ woff,
                                                      int2* __restrict__ sorted2, int E)
{
    int e = blockIdx.x * 256 + threadIdx.x;
    if (e < E) {
        int pos = atomicAdd(&woff[dstv[e]], 1);
        sorted2[pos] = make_int2(srcv[e], e);
    }
}

// ---------------------------------------------------------------------------
// Weight cast+transpose: w [K,256] f32 -> wT [256][K] bf16
// ---------------------------------------------------------------------------
__global__ __launch_bounds__(256) void castT_kernel(const float* __restrict__ w,
                                                    unsigned short* __restrict__ out, int K)
{
    int i = blockIdx.x * 256 + threadIdx.x;
    if (i < K * 256) {
        int k = i >> 8, c = i & 255;
        out[c * K + k] = f2b(w[i]);
    }
}

// ---------------------------------------------------------------------------
// Gather aggregation, one wave per node (round-0 topology).
//
// ROUND-8: rocprof across rounds 0-7 (VGPR_Count pinned at ~48 regardless
// of pins / waves_per_eu / SGPR-staging) proves the allocator NEVER holds
// the 16xD weight slice in registers — it remats it as ~16 L1 loads +
// address math PER EDGE (the measured ~108 instr/edge vs ~40 useful).
// Fix: weights + bias live in LDS ([17][D], 17KB for D=256 — no occupancy
// impact), read per K-row with ds_read_b128 at wave-constant base +
// IMMEDIATE offset: zero address VALU, zero VMEM-queue pressure,
// canonical conflict-free stride-16B pattern. Edges processed in PAIRS
// sharing each weight read (17 ds_reads serve 64 pk_fma), balancing the
// LDS pipe (~17 cy/edge/CU) against VALU (~16 cy/edge/CU). Ping-pong
// dropped (its 32-reg ea buffer was the pressure source); TLP hides
// per-pair load latency. Per-edge FMA dag and edge order unchanged ->
// bit-identical results.
// ---------------------------------------------------------------------------
template<int D, bool XB>
__global__ __launch_bounds__(256) void agg_kernel(
    const float*          __restrict__ xf,
    const unsigned short* __restrict__ xb,
    const float*          __restrict__ ea,     // [E, 16]
    const float*          __restrict__ ew,     // [16, D]
    const float*          __restrict__ ebias,  // [D]
    const int*            __restrict__ row_start,
    const int*            __restrict__ cnt,
    const int2*           __restrict__ sorted2, // [E] {src, eid}
    float*                __restrict__ agg,    // [N, D]
    int N)
{
    constexpr int DPL = D / 64;     // dims per lane
    constexpr int NP  = DPL / 2;    // f32x2 pairs per lane
    using XT = std::conditional_t<XB, ushort4,
               std::conditional_t<DPL == 2, float2, float4>>;

    __shared__ float wlds[17 * D];  // rows 0..15 = ew, row 16 = bias

    const int tid = threadIdx.x;
#pragma unroll
    for (int ci = tid; ci < (17 * D) / 4; ci += 256) {
        int f0 = ci * 4;
        float4 v;
        if (f0 < 16 * D) v = *reinterpret_cast<const float4*>(ew + f0);
        else             v = *reinterpret_cast<const float4*>(ebias + (f0 - 16 * D));
        *reinterpret_cast<float4*>(&wlds[f0]) = v;
    }
    __syncthreads();

    const int lane = tid & 63;
    const int node = blockIdx.x * 4 + (tid >> 6);
    if (node >= N) return;
    const int d0 = lane * DPL;

    // bias pairs (from LDS; cheap to re-read if the allocator remats)
    f32x2 bxp[NP];
    if constexpr (NP == 1) {
        float2 bb = *reinterpret_cast<const float2*>(&wlds[16 * D + d0]);
        bxp[0] = f32x2{bb.x, bb.y};
    } else {
        float4 bb = *reinterpret_cast<const float4*>(&wlds[16 * D + d0]);
        bxp[0] = f32x2{bb.x, bb.y};
        bxp[1] = f32x2{bb.z, bb.w};
    }

    f32x2 acc[NP];
#pragma unroll
    for (int p = 0; p < NP; ++p) acc[p] = f32x2{0.f, 0.f};

    const int s0 = __builtin_amdgcn_readfirstlane(row_start[node]);
    const int c  = __builtin_amdgcn_readfirstlane(cnt[node]);

    // load one edge's ea row (broadcast) + x slice
    auto LOADE = [&](int2 prv, int idx, float4* E, XT& X) {
        int s = __builtin_amdgcn_readlane(prv.x, idx);
        int e = __builtin_amdgcn_readlane(prv.y, idx);
        const float4* p = reinterpret_cast<const float4*>(ea + (size_t)e * 16);
        E[0] = p[0]; E[1] = p[1]; E[2] = p[2]; E[3] = p[3];
        if constexpr (XB) X = *reinterpret_cast<const XT*>(xb + (size_t)s * D + d0);
        else              X = *reinterpret_cast<const XT*>(xf + (size_t)s * D + d0);
    };

    // repack ea float4s into 8 f32x2 (aliases of the load registers)
    auto PAIRS = [&](const float4* E, f32x2* ap) {
        ap[0] = f32x2{E[0].x, E[0].y}; ap[1] = f32x2{E[0].z, E[0].w};
        ap[2] = f32x2{E[1].x, E[1].y}; ap[3] = f32x2{E[1].z, E[1].w};
        ap[4] = f32x2{E[2].x, E[2].y}; ap[5] = f32x2{E[2].z, E[2].w};
        ap[6] = f32x2{E[3].x, E[3].y}; ap[7] = f32x2{E[3].z, E[3].w};
    };

    auto MINIT = [&](const XT& X, f32x2* m) {
        if constexpr (XB) {
            m[0] = bxp[0] + f32x2{b2f(X.x), b2f(X.y)};
            m[1] = bxp[1] + f32x2{b2f(X.z), b2f(X.w)};
        } else if constexpr (NP == 1) {
            m[0] = bxp[0] + f32x2{X.x, X.y};
        } else {
            m[0] = bxp[0] + f32x2{X.x, X.y};
            m[1] = bxp[1] + f32x2{X.z, X.w};
        }
    };

    // K-loop over 8 row pairs; weight reads shared by both edges of a pair
    auto KLOOP2 = [&](const f32x2* aA, f32x2* mA, const f32x2* aB, f32x2* mB) {
#pragma unroll
        for (int k2 = 0; k2 < 8; ++k2) {
            f32x2 we[NP], wo[NP];
            if constexpr (NP == 1) {
                float2 w0 = *reinterpret_cast<const float2*>(&wlds[(2 * k2) * D + d0]);
                float2 w1 = *reinterpret_cast<const float2*>(&wlds[(2 * k2 + 1) * D + d0]);
                we[0] = f32x2{w0.x, w0.y};
                wo[0] = f32x2{w1.x, w1.y};
            } else {
                float4 w0 = *reinterpret_cast<const float4*>(&wlds[(2 * k2) * D + d0]);
                float4 w1 = *reinterpret_cast<const float4*>(&wlds[(2 * k2 + 1) * D + d0]);
                we[0] = f32x2{w0.x, w0.y}; we[1] = f32x2{w0.z, w0.w};
                wo[0] = f32x2{w1.x, w1.y}; wo[1] = f32x2{w1.z, w1.w};
            }
#pragma unroll
            for (int p = 0; p < NP; ++p) mA[p] = pk_fma_lo(aA[k2], we[p], mA[p]);
#pragma unroll
            for (int p = 0; p < NP; ++p) mA[p] = pk_fma_hi(aA[k2], wo[p], mA[p]);
#pragma unroll
            for (int p = 0; p < NP; ++p) mB[p] = pk_fma_lo(aB[k2], we[p], mB[p]);
#pragma unroll
            for (int p = 0; p < NP; ++p) mB[p] = pk_fma_hi(aB[k2], wo[p], mB[p]);
        }
    };

    auto KLOOP1 = [&](const f32x2* aA, f32x2* mA) {
#pragma unroll
        for (int k2 = 0; k2 < 8; ++k2) {
            f32x2 we[NP], wo[NP];
            if constexpr (NP == 1) {
                float2 w0 = *reinterpret_cast<const float2*>(&wlds[(2 * k2) * D + d0]);
                float2 w1 = *reinterpret_cast<const float2*>(&wlds[(2 * k2 + 1) * D + d0]);
                we[0] = f32x2{w0.x, w0.y};
                wo[0] = f32x2{w1.x, w1.y};
            } else {
                float4 w0 = *reinterpret_cast<const float4*>(&wlds[(2 * k2) * D + d0]);
                float4 w1 = *reinterpret_cast<const float4*>(&wlds[(2 * k2 + 1) * D + d0]);
                we[0] = f32x2{w0.x, w0.y}; we[1] = f32x2{w0.z, w0.w};
                wo[0] = f32x2{w1.x, w1.y}; wo[1] = f32x2{w1.z, w1.w};
            }
#pragma unroll
            for (int p = 0; p < NP; ++p) mA[p] = pk_fma_lo(aA[k2], we[p], mA[p]);
#pragma unroll
            for (int p = 0; p < NP; ++p) mA[p] = pk_fma_hi(aA[k2], wo[p], mA[p]);
        }
    };

    for (int base = 0; base < c; base += 64) {
        const int cc = min(64, c - base);

        int2 pr = make_int2(0, 0);
        if (lane < cc) pr = sorted2[s0 + base + lane];

        float4 EA[4], EB[4]; XT xA, xB;
        f32x2 apA[8], apB[8], mA[NP], mB[NP];

        int i = 0;
        while (i + 1 < cc) {                   // edge pairs sharing w-reads
            LOADE(pr, i,     EA, xA);
            LOADE(pr, i + 1, EB, xB);
            PAIRS(EA, apA); PAIRS(EB, apB);
            MINIT(xA, mA);  MINIT(xB, mB);
            KLOOP2(apA, mA, apB, mB);
#pragma unroll
            for (int p = 0; p < NP; ++p) acc[p] = acc[p] + vrelu(mA[p]);
#pragma unroll
            for (int p = 0; p < NP; ++p) acc[p] = acc[p] + vrelu(mB[p]);
            i += 2;
        }
        if (i < cc) {                          // odd tail
            LOADE(pr, i, EA, xA);
            PAIRS(EA, apA);
            MINIT(xA, mA);
            KLOOP1(apA, mA);
#pragma unroll
            for (int p = 0; p < NP; ++p) acc[p] = acc[p] + vrelu(mA[p]);
        }
    }

    if constexpr (NP == 1)
        *reinterpret_cast<float2*>(agg + (size_t)node * D + d0) =
            make_float2(acc[0].x, acc[0].y);
    else
        *reinterpret_cast<float4*>(agg + (size_t)node * D + d0) =
            make_float4(acc[0].x, acc[0].y, acc[1].x, acc[1].y);
}

// ---------------------------------------------------------------------------
// Fused node MLP via MFMA bf16 (unchanged)
// ---------------------------------------------------------------------------
template<int DIN, bool L1>
__global__ __launch_bounds__(256) void node_mfma_kernel(
    const float*          __restrict__ basef,
    const unsigned short* __restrict__ baseb,
    const float*          __restrict__ agg,
    const unsigned short* __restrict__ w1T,
    const float*          __restrict__ b1,
    const unsigned short* __restrict__ w2T,
    const float*          __restrict__ b2,
    unsigned short*       __restrict__ outb,
    float*                __restrict__ outf,
    int N)
{
    __shared__ unsigned short hs[64 * DIN];
    __shared__ unsigned short ts[64 * 256];
    const int tid = threadIdx.x;
    const int n0 = blockIdx.x * 64;

#pragma unroll
    for (int it = 0; it < (64 * DIN) / (256 * 8); ++it) {
        int flat = (it * 256 + tid) * 8;
        int r = flat / DIN, c = flat % DIN;
        int node = n0 + r;
        float v[8];
        if (node < N) {
            const float* ap = agg + (size_t)node * DIN + c;
            float4 a0 = *reinterpret_cast<const float4*>(ap);
            float4 a1 = *reinterpret_cast<const float4*>(ap + 4);
            float a[8] = {a0.x, a0.y, a0.z, a0.w, a1.x, a1.y, a1.z, a1.w};
            if constexpr (L1) {
                const float* bp = basef + (size_t)node * DIN + c;
                float4 x0 = *reinterpret_cast<const float4*>(bp);
                float4 x1 = *reinterpret_cast<const float4*>(bp + 4);
                float xx[8] = {x0.x, x0.y, x0.z, x0.w, x1.x, x1.y, x1.z, x1.w};
#pragma unroll
                for (int j = 0; j < 8; ++j) v[j] = a[j] + xx[j];
            } else {
                short8 xv = *reinterpret_cast<const short8*>(baseb + (size_t)node * DIN + c);
#pragma unroll
                for (int j = 0; j < 8; ++j) v[j] = a[j] + b2f((unsigned short)xv[j]);
            }
        } else {
#pragma unroll
            for (int j = 0; j < 8; ++j) v[j] = 0.f;
        }
        short8 o;
#pragma unroll
        for (int j = 0; j < 8; ++j) o[j] = (short)f2b(v[j]);
        *reinterpret_cast<short8*>(&hs[r * DIN + (c ^ ((r & 7) << 3))]) = o;
    }
    __syncthreads();

    const int wv = tid >> 6, lane = tid & 63;
    const int lr = lane & 15, lk = (lane >> 4) * 8;
    const int colbase = wv * 64;

    floatx4 acc[4][4];
#pragma unroll
    for (int n = 0; n < 4; ++n) {
        float bn = b1[colbase + n * 16 + lr];
#pragma unroll
        for (int m = 0; m < 4; ++m) acc[m][n] = floatx4{bn, bn, bn, bn};
    }
#pragma unroll
    for (int kk = 0; kk < DIN; kk += 32) {
        short8 af[4], bf[4];
#pragma unroll
        for (int m = 0; m < 4; ++m) {
            int row = m * 16 + lr;
            af[m] = *reinterpret_cast<const short8*>(
                &hs[row * DIN + ((kk + lk) ^ ((row & 7) << 3))]);
        }
#pragma unroll
        for (int n = 0; n < 4; ++n) {
            int col = colbase + n * 16 + lr;
            bf[n] = *reinterpret_cast<const short8*>(w1T + (size_t)col * DIN + kk + lk);
        }
#pragma unroll
        for (int m = 0; m < 4; ++m)
#pragma unroll
            for (int n = 0; n < 4; ++n)
                acc[m][n] = __builtin_amdgcn_mfma_f32_16x16x32_bf16(af[m], bf[n], acc[m][n], 0, 0, 0);
    }
#pragma unroll
    for (int m = 0; m < 4; ++m)
#pragma unroll
        for (int n = 0; n < 4; ++n)
#pragma unroll
            for (int r = 0; r < 4; ++r) {
                int row = m * 16 + (lane >> 4) * 4 + r;
                int col = colbase + n * 16 + lr;
                ts[row * 256 + (col ^ ((row & 7) << 3))] = f2b(fmaxf(acc[m][n][r], 0.f));
            }
    __syncthreads();

    floatx4 acc2[4][4];
#pragma unroll
    for (int n = 0; n < 4; ++n) {
        float bn = b2[colbase + n * 16 + lr];
#pragma unroll
        for (int m = 0; m < 4; ++m) acc2[m][n] = floatx4{bn, bn, bn, bn};
    }
#pragma unroll
    for (int kk = 0; kk < 256; kk += 32) {
        short8 af[4], bf[4];
#pragma unroll
        for (int m = 0; m < 4; ++m) {
            int row = m * 16 + lr;
            af[m] = *reinterpret_cast<const short8*>(
                &ts[row * 256 + ((kk + lk) ^ ((row & 7) << 3))]);
        }
#pragma unroll
        for (int n = 0; n < 4; ++n) {
            int col = colbase + n * 16 + lr;
            bf[n] = *reinterpret_cast<const short8*>(w2T + (size_t)col * 256 + kk + lk);
        }
#pragma unroll
        for (int m = 0; m < 4; ++m)
#pragma unroll
            for (int n = 0; n < 4; ++n)
                acc2[m][n] = __builtin_amdgcn_mfma_f32_16x16x32_bf16(af[m], bf[n], acc2[m][n], 0, 0, 0);
    }
#pragma unroll
    for (int m = 0; m < 4; ++m)
#pragma unroll
        for (int n = 0; n < 4; ++n)
#pragma unroll
            for (int r = 0; r < 4; ++r) {
                int row = m * 16 + (lane >> 4) * 4 + r;
                int node = n0 + row;
                int col = colbase + n * 16 + lr;
                if (node < N) {
                    if constexpr (L1) outb[(size_t)node * 256 + col] = f2b(acc2[m][n][r]);
                    else              outf[(size_t)node * 256 + col] = acc2[m][n][r];
                }
            }
}

// ---------------------------------------------------------------------------
extern "C" void kernel_launch(void* const* d_in, const int* in_sizes, int n_in,
                              void* d_out, int out_size, void* d_ws, size_t ws_size,
                              hipStream_t stream)
{
    const float* x    = (const float*)d_in[0];
    const int*   ei   = (const int*)  d_in[1];
    const float* ea   = (const float*)d_in[2];
    const float* e1w  = (const float*)d_in[3];
    const float* e1b  = (const float*)d_in[4];
    const float* w11  = (const float*)d_in[5];
    const float* b11  = (const float*)d_in[6];
    const float* w12  = (const float*)d_in[7];
    const float* b12  = (const float*)d_in[8];
    const float* e2w  = (const float*)d_in[9];
    const float* e2b  = (const float*)d_in[10];
    const float* w21  = (const float*)d_in[11];
    const float* b21  = (const float*)d_in[12];
    const float* w22  = (const float*)d_in[13];
    const float* b22  = (const float*)d_in[14];

    const int E = in_sizes[1] / 2;
    const int N = N_NODES;
    const int* src = ei;
    const int* dst = ei + E;

    // ---- workspace layout
    char* cur = (char*)d_ws;
    float* aggb = (float*)cur;            cur += (size_t)N * 256 * 4;
    int*   cnt       = (int*)cur;         cur += (size_t)N * 4;
    int*   row_start = (int*)cur;         cur += (size_t)N * 4;
    int*   woff      = (int*)cur;         cur += (size_t)N * 4;
    int*   bsum      = (int*)cur;         cur += 256 * 4;
    int2*  sorted2   = (int2*)cur;        cur += (size_t)E * 8;
    unsigned short* h1b  = (unsigned short*)cur; cur += (size_t)N * 256 * 2;
    unsigned short* w11T = (unsigned short*)cur; cur += 128 * 256 * 2;
    unsigned short* w12T = (unsigned short*)cur; cur += 256 * 256 * 2;
    unsigned short* w21T = (unsigned short*)cur; cur += 256 * 256 * 2;
    unsigned short* w22T = (unsigned short*)cur; cur += 256 * 256 * 2;
    float* outp = (float*)d_out;

    const int nbN = (N + 255) / 256;
    const int nbE = (E + 255) / 256;

    // ---- weight casts
    castT_kernel<<<(128 * 256 + 255) / 256, 256, 0, stream>>>(w11, w11T, 128);
    castT_kernel<<<256, 256, 0, stream>>>(w12, w12T, 256);
    castT_kernel<<<256, 256, 0, stream>>>(w21, w21T, 256);
    castT_kernel<<<256, 256, 0, stream>>>(w22, w22T, 256);

    // ---- CSR build (shared by both layers)
    zero_int_kernel<<<nbN, 256, 0, stream>>>(cnt, N);
    hist_kernel<<<nbE, 256, 0, stream>>>(dst, cnt, E);
    scanA_kernel<<<nbN, 256, 0, stream>>>(cnt, row_start, bsum, N);
    scanB_kernel<<<1, 256, 0, stream>>>(bsum, nbN);
    scanC_kernel<<<nbN, 256, 0, stream>>>(row_start, woff, bsum, N);
    scatter_kernel<<<nbE, 256, 0, stream>>>(src, dst, woff, sorted2, E);

    const int nbAgg  = (N + 3) / 4;
    const int nbNode = (N + 63) / 64;

    // ---- layer 1
    agg_kernel<128, false><<<nbAgg, 256, 0, stream>>>(
        x, nullptr, ea, e1w, e1b, row_start, cnt, sorted2, aggb, N);
    node_mfma_kernel<128, true><<<nbNode, 256, 0, stream>>>(
        x, nullptr, aggb, w11T, b11, w12T, b12, h1b, nullptr, N);

    // ---- layer 2
    agg_kernel<256, true><<<nbAgg, 256, 0, stream>>>(
        nullptr, h1b, ea, e2w, e2b, row_start, cnt, sorted2, aggb, N);
    node_mfma_kernel<256, false><<<nbNode, 256, 0, stream>>>(
        nullptr, h1b, aggb, w21T, b21, w22T, b22, nullptr, outp, N);
}